// Round 6
// baseline (20105.380 us; speedup 1.0000x reference)
//
#include <hip/hip_runtime.h>
#include <stdint.h>
#include <math.h>

#define B_ 64
#define S_ 512
#define I_ 128
#define H_ 2048
#define O_ 128
#define NWG 128
#define COLS 16
#define NTHREADS 256
#define SLAB (B_ * H_)      /* 131072 elements per h snapshot */
#define RSTR 20             /* sRed row stride in floats */
#define CANARY64 0xAAAAAAAAAAAAAAAAull

typedef __attribute__((ext_vector_type(8))) __bf16 bf16x8;
typedef __attribute__((ext_vector_type(4))) float floatx4;
typedef unsigned long long ull;

__device__ __forceinline__ unsigned short f2bf(float f) {
    unsigned u = __float_as_uint(f);
    unsigned r = u + 0x7fffu + ((u >> 16) & 1u);   // RNE
    return (unsigned short)(r >> 16);
}
__device__ __forceinline__ float bf2f(unsigned short h) {
    return __uint_as_float(((unsigned)h) << 16);
}
// tanh(x) = 1 - 2/(e^{2x}+1); err ~1e-6 << bf16 noise.
__device__ __forceinline__ float fast_tanh(float x) {
    float e = __expf(2.0f * x);
    return 1.0f - 2.0f * __builtin_amdgcn_rcpf(e + 1.0f);
}

// ---- prep kernels -------------------------------------------------------
__global__ void k_wsplit(const float* __restrict__ whh, const float* __restrict__ mask,
                         unsigned short* __restrict__ hi, unsigned short* __restrict__ lo, int n) {
    int i = blockIdx.x * blockDim.x + threadIdx.x;
    int stride = gridDim.x * blockDim.x;
    for (; i < n; i += stride) {
        float w = whh[i] * mask[i];
        unsigned short h = f2bf(w);
        hi[i] = h;
        lo[i] = f2bf(w - bf2f(h));
    }
}
__global__ void k_split(const float* __restrict__ src,
                        unsigned short* __restrict__ hi, unsigned short* __restrict__ lo, int n) {
    int i = blockIdx.x * blockDim.x + threadIdx.x;
    int stride = gridDim.x * blockDim.x;
    for (; i < n; i += stride) {
        float w = src[i];
        unsigned short h = f2bf(w);
        hi[i] = h;
        lo[i] = f2bf(w - bf2f(h));
    }
}
__global__ void k_cast(const float* __restrict__ src, unsigned short* __restrict__ dst, int n) {
    int i = blockIdx.x * blockDim.x + threadIdx.x;
    int stride = gridDim.x * blockDim.x;
    for (; i < n; i += stride) dst[i] = f2bf(src[i]);
}
// fill h slabs 1..S with the canary pattern (data-as-sync sentinel)
__global__ void k_canary(ull* __restrict__ dst, size_t n) {
    size_t i = (size_t)blockIdx.x * blockDim.x + threadIdx.x;
    size_t stride = (size_t)gridDim.x * blockDim.x;
    for (; i < n; i += stride) dst[i] = CANARY64;
}

// ---- persistent recurrence kernel --------------------------------------
// 128 WGs x 256 thr; WG owns 16 output cols; split-K over 4 waves.
// Round-6 sync: DATA-AS-SYNC. No flags, no vmcnt drains, no publish
// barrier. h slabs are pre-filled with CANARY; producers store h via
// agent-scope relaxed 8-B stores and move on; consumers read via
// agent-scope relaxed 8-B loads (stale-proof at the coherence point),
// compare against CANARY, and retry only stale chunks. Producer store
// units and consumer load units are the same 4-col-aligned 8-B words,
// so no tearing. Depth-4 prefetch pipeline over the 16 K-chunks.
__global__ __launch_bounds__(NTHREADS, 1) void k_rnn(
    const unsigned short* __restrict__ whi, const unsigned short* __restrict__ wlo,
    const unsigned short* __restrict__ wihh, const unsigned short* __restrict__ wihl,
    const unsigned short* __restrict__ xbf, const float* __restrict__ bih,
    unsigned short* hs)
{
    __shared__ float sRed[2][4 * 64 * RSTR];
    __shared__ float sBih[COLS];

    const int tid  = threadIdx.x;
    const int wg   = blockIdx.x;
    const int j0   = wg * COLS;
    const int w    = tid >> 6;
    const int lane = tid & 63;
    const int q    = lane >> 4;
    const int nn   = lane & 15;
    const int kb   = w * 512;   // this wave's k range in H
    const int xkb  = w * 32;    // this wave's k range in I

    if (tid < COLS) sBih[tid] = bih[j0 + tid];

    // Preload W fragments (time-invariant B-operands)
    bf16x8 wh[16], wl[16], bxh, bxl;
    {
        const size_t wrow = (size_t)(j0 + nn) * H_ + (size_t)(kb + q * 8);
#pragma unroll
        for (int ks = 0; ks < 16; ++ks) {
            wh[ks] = *(const bf16x8*)&whi[wrow + ks * 32];
            wl[ks] = *(const bf16x8*)&wlo[wrow + ks * 32];
        }
        const size_t xrow = (size_t)(j0 + nn) * I_ + (size_t)(xkb + q * 8);
        bxh = *(const bf16x8*)&wihh[xrow];
        bxl = *(const bf16x8*)&wihl[xrow];
    }

#pragma unroll 1
    for (int t = 0; t < S_; ++t) {
        const unsigned short* hp = hs + (size_t)t * SLAB;
        floatx4 a0 = {0.f, 0.f, 0.f, 0.f}, a1 = a0, a2 = a0, a3 = a0;

        // h-independent x-projection first
        {
            const size_t xoff = (size_t)t * I_ + xkb + q * 8;
            bf16x8 x0 = *(const bf16x8*)&xbf[(size_t)(nn)      * (S_ * I_) + xoff];
            bf16x8 x1 = *(const bf16x8*)&xbf[(size_t)(16 + nn) * (S_ * I_) + xoff];
            bf16x8 x2 = *(const bf16x8*)&xbf[(size_t)(32 + nn) * (S_ * I_) + xoff];
            bf16x8 x3 = *(const bf16x8*)&xbf[(size_t)(48 + nn) * (S_ * I_) + xoff];
            a0 = __builtin_amdgcn_mfma_f32_16x16x32_bf16(x0, bxh, a0, 0, 0, 0);
            a1 = __builtin_amdgcn_mfma_f32_16x16x32_bf16(x1, bxh, a1, 0, 0, 0);
            a2 = __builtin_amdgcn_mfma_f32_16x16x32_bf16(x2, bxh, a2, 0, 0, 0);
            a3 = __builtin_amdgcn_mfma_f32_16x16x32_bf16(x3, bxh, a3, 0, 0, 0);
            a0 = __builtin_amdgcn_mfma_f32_16x16x32_bf16(x0, bxl, a0, 0, 0, 0);
            a1 = __builtin_amdgcn_mfma_f32_16x16x32_bf16(x1, bxl, a1, 0, 0, 0);
            a2 = __builtin_amdgcn_mfma_f32_16x16x32_bf16(x2, bxl, a2, 0, 0, 0);
            a3 = __builtin_amdgcn_mfma_f32_16x16x32_bf16(x3, bxl, a3, 0, 0, 0);
        }

        // row-group base pointers into slab t (8-B units, 4 cols each)
        ull* hq0 = (ull*)(hp + (size_t)(nn)      * H_ + kb + q * 8);
        ull* hq1 = (ull*)(hp + (size_t)(16 + nn) * H_ + kb + q * 8);
        ull* hq2 = (ull*)(hp + (size_t)(32 + nn) * H_ + kb + q * 8);
        ull* hq3 = (ull*)(hp + (size_t)(48 + nn) * H_ + kb + q * 8);

        ull L[4][8];   // 4 pipeline slots x (4 row-groups x 2 halves)

#define LOAD8(s, ks_)                                                          \
        do { const int o_ = (ks_) * 8;                                         \
            L[s][0] = __hip_atomic_load(&hq0[o_],     __ATOMIC_RELAXED, __HIP_MEMORY_SCOPE_AGENT); \
            L[s][1] = __hip_atomic_load(&hq0[o_ + 1], __ATOMIC_RELAXED, __HIP_MEMORY_SCOPE_AGENT); \
            L[s][2] = __hip_atomic_load(&hq1[o_],     __ATOMIC_RELAXED, __HIP_MEMORY_SCOPE_AGENT); \
            L[s][3] = __hip_atomic_load(&hq1[o_ + 1], __ATOMIC_RELAXED, __HIP_MEMORY_SCOPE_AGENT); \
            L[s][4] = __hip_atomic_load(&hq2[o_],     __ATOMIC_RELAXED, __HIP_MEMORY_SCOPE_AGENT); \
            L[s][5] = __hip_atomic_load(&hq2[o_ + 1], __ATOMIC_RELAXED, __HIP_MEMORY_SCOPE_AGENT); \
            L[s][6] = __hip_atomic_load(&hq3[o_],     __ATOMIC_RELAXED, __HIP_MEMORY_SCOPE_AGENT); \
            L[s][7] = __hip_atomic_load(&hq3[o_ + 1], __ATOMIC_RELAXED, __HIP_MEMORY_SCOPE_AGENT); \
        } while (0)

        LOAD8(0, 0); LOAD8(1, 1); LOAD8(2, 2); LOAD8(3, 3);

#pragma unroll 1
        for (int ks = 0; ks < 16; ++ks) {
            const int s = ks & 3;
            // validate: any 8-B unit still canary in any lane -> reload
            for (;;) {
                bool stale = (L[s][0] == CANARY64) | (L[s][1] == CANARY64) |
                             (L[s][2] == CANARY64) | (L[s][3] == CANARY64) |
                             (L[s][4] == CANARY64) | (L[s][5] == CANARY64) |
                             (L[s][6] == CANARY64) | (L[s][7] == CANARY64);
                if (__ballot(stale) == 0ull) break;
                LOAD8(s, ks);
            }
            union { ull u[2]; bf16x8 v; } h0, h1, h2, h3;
            h0.u[0] = L[s][0]; h0.u[1] = L[s][1];
            h1.u[0] = L[s][2]; h1.u[1] = L[s][3];
            h2.u[0] = L[s][4]; h2.u[1] = L[s][5];
            h3.u[0] = L[s][6]; h3.u[1] = L[s][7];
            a0 = __builtin_amdgcn_mfma_f32_16x16x32_bf16(h0.v, wh[ks], a0, 0, 0, 0);
            a1 = __builtin_amdgcn_mfma_f32_16x16x32_bf16(h1.v, wh[ks], a1, 0, 0, 0);
            a2 = __builtin_amdgcn_mfma_f32_16x16x32_bf16(h2.v, wh[ks], a2, 0, 0, 0);
            a3 = __builtin_amdgcn_mfma_f32_16x16x32_bf16(h3.v, wh[ks], a3, 0, 0, 0);
            a0 = __builtin_amdgcn_mfma_f32_16x16x32_bf16(h0.v, wl[ks], a0, 0, 0, 0);
            a1 = __builtin_amdgcn_mfma_f32_16x16x32_bf16(h1.v, wl[ks], a1, 0, 0, 0);
            a2 = __builtin_amdgcn_mfma_f32_16x16x32_bf16(h2.v, wl[ks], a2, 0, 0, 0);
            a3 = __builtin_amdgcn_mfma_f32_16x16x32_bf16(h3.v, wl[ks], a3, 0, 0, 0);
            if (ks < 12) LOAD8(s, ks + 4);
        }
#undef LOAD8

        // wave partials -> LDS (buffer t&1)
        float* sr = sRed[t & 1];
#pragma unroll
        for (int r = 0; r < 4; ++r) {
            sr[(w * 64 +      q * 4 + r) * RSTR + nn] = a0[r];
            sr[(w * 64 + 16 + q * 4 + r) * RSTR + nn] = a1[r];
            sr[(w * 64 + 32 + q * 4 + r) * RSTR + nn] = a2[r];
            sr[(w * 64 + 48 + q * 4 + r) * RSTR + nn] = a3[r];
        }
        __syncthreads();   // the ONE barrier per step

        // reduce 4 waves, +bih, tanh, pack, 8-B agent store. No drain,
        // no flag: the data itself is the sync token.
        {
            const int m  = tid >> 2;          // batch row 0..63
            const int n0 = (tid & 3) * 4;     // local col 0,4,8,12
            floatx4 s = *(const floatx4*)&sr[(0 * 64 + m) * RSTR + n0];
            s += *(const floatx4*)&sr[(1 * 64 + m) * RSTR + n0];
            s += *(const floatx4*)&sr[(2 * 64 + m) * RSTR + n0];
            s += *(const floatx4*)&sr[(3 * 64 + m) * RSTR + n0];
            union { unsigned short u4[4]; ull u64; } cv;
            cv.u4[0] = f2bf(fast_tanh(s[0] + sBih[n0 + 0]));
            cv.u4[1] = f2bf(fast_tanh(s[1] + sBih[n0 + 1]));
            cv.u4[2] = f2bf(fast_tanh(s[2] + sBih[n0 + 2]));
            cv.u4[3] = f2bf(fast_tanh(s[3] + sBih[n0 + 3]));
            ull* dst = (ull*)&hs[(size_t)(t + 1) * SLAB + (size_t)m * H_ + j0 + n0];
            __hip_atomic_store(dst, cv.u64, __ATOMIC_RELAXED, __HIP_MEMORY_SCOPE_AGENT);
        }
    }
}

// ---- output projection: out[b,t,o] = hs[t+1][b,:] . Who[o,:] + bho ------
__global__ __launch_bounds__(NTHREADS) void k_out(
    const unsigned short* __restrict__ hflat, const unsigned short* __restrict__ who,
    const float* __restrict__ bho, float* __restrict__ out)
{
    const int tid = threadIdx.x;
    const int w = tid >> 6, lane = tid & 63, q = lane >> 4, nn = lane & 15;
    const size_t r0 = ((size_t)blockIdx.x * 4 + w) * 16;   // row = t*64+b
    floatx4 acc[8];
#pragma unroll
    for (int i = 0; i < 8; ++i) acc[i] = floatx4{0.f, 0.f, 0.f, 0.f};
    for (int ks = 0; ks < 64; ++ks) {
        const int kk = ks * 32 + q * 8;
        bf16x8 a = *(const bf16x8*)&hflat[(r0 + nn) * H_ + kk];
#pragma unroll
        for (int nt = 0; nt < 8; ++nt) {
            bf16x8 b = *(const bf16x8*)&who[(size_t)(nt * 16 + nn) * H_ + kk];
            acc[nt] = __builtin_amdgcn_mfma_f32_16x16x32_bf16(a, b, acc[nt], 0, 0, 0);
        }
    }
#pragma unroll
    for (int nt = 0; nt < 8; ++nt) {
#pragma unroll
        for (int r = 0; r < 4; ++r) {
            size_t rr = r0 + q * 4 + r;
            int t = (int)(rr >> 6), b = (int)(rr & 63);
            int o = nt * 16 + nn;
            out[(size_t)b * (S_ * O_) + (size_t)t * O_ + o] = acc[nt][r] + bho[o];
        }
    }
}

// ---- host ----------------------------------------------------------------
extern "C" void kernel_launch(void* const* d_in, const int* in_sizes, int n_in,
                              void* d_out, int out_size, void* d_ws, size_t ws_size,
                              hipStream_t stream) {
    const float* x    = (const float*)d_in[0];
    const float* Wih  = (const float*)d_in[1];
    const float* bih  = (const float*)d_in[2];
    const float* Whh  = (const float*)d_in[3];
    const float* Who  = (const float*)d_in[4];
    const float* bho  = (const float*)d_in[5];
    const float* mask = (const float*)d_in[6];
    float* out = (float*)d_out;

    char* ws = (char*)d_ws;
    constexpr size_t HS_OFF   = 0;
    constexpr size_t HS_BYTES = (size_t)(S_ + 1) * SLAB * 2;
    constexpr size_t WHI_OFF  = HS_OFF + HS_BYTES;
    constexpr size_t WLO_OFF  = WHI_OFF + (size_t)H_ * H_ * 2;
    constexpr size_t XBF_OFF  = WLO_OFF + (size_t)H_ * H_ * 2;
    constexpr size_t WIHH_OFF = XBF_OFF + (size_t)B_ * S_ * I_ * 2;
    constexpr size_t WIHL_OFF = WIHH_OFF + (size_t)H_ * I_ * 2;
    constexpr size_t WHO_OFF  = WIHL_OFF + (size_t)H_ * I_ * 2;
    constexpr size_t WS_NEED  = WHO_OFF + (size_t)O_ * H_ * 2;
    if (ws_size < WS_NEED) return;

    unsigned short* hs    = (unsigned short*)(ws + HS_OFF);
    unsigned short* whi   = (unsigned short*)(ws + WHI_OFF);
    unsigned short* wlo   = (unsigned short*)(ws + WLO_OFF);
    unsigned short* xbf   = (unsigned short*)(ws + XBF_OFF);
    unsigned short* wihh  = (unsigned short*)(ws + WIHH_OFF);
    unsigned short* wihl  = (unsigned short*)(ws + WIHL_OFF);
    unsigned short* whobf = (unsigned short*)(ws + WHO_OFF);

    hipMemsetAsync(hs, 0, (size_t)SLAB * 2, stream);      // h_{-1} = 0 (valid!)
    // canary-fill slabs 1..S (the sync sentinel)
    k_canary<<<2048, 256, 0, stream>>>((ull*)(hs + SLAB), (size_t)S_ * SLAB / 4);

    k_wsplit<<<1024, 256, 0, stream>>>(Whh, mask, whi, wlo, H_ * H_);
    k_split <<<256, 256, 0, stream>>>(Wih, wihh, wihl, H_ * I_);
    k_cast  <<<256, 256, 0, stream>>>(Who, whobf, O_ * H_);
    k_cast  <<<1024, 256, 0, stream>>>(x, xbf, B_ * S_ * I_);

    k_rnn<<<NWG, NTHREADS, 0, stream>>>(whi, wlo, wihh, wihl, xbf, bih, hs);
    k_out<<<512, NTHREADS, 0, stream>>>(hs + SLAB, whobf, bho, out);
}

// Round 7
// 5894.876 us; speedup vs baseline: 3.4107x; 3.4107x over previous
//
#include <hip/hip_runtime.h>
#include <stdint.h>
#include <math.h>

#define B_ 64
#define S_ 512
#define I_ 128
#define H_ 2048
#define O_ 128
#define NREP 8            /* replicas = XCDs */
#define WPR 32            /* WGs per replica */
#define COLS 64           /* output cols per WG */
#define ROWS 8            /* batch rows per replica */
#define NTHREADS 512      /* 8 waves per WG */
#define SLABX (ROWS * H_) /* 16384 elems per replica h-slab */
#define FST 64            /* flag stride per replica (u32) */
#define RW 68             /* sRed row stride (floats) */
#define RWAVE (8 * RW + 4)/* sRed wave stride = 548 floats */

typedef __attribute__((ext_vector_type(8))) __bf16 bf16x8;
typedef __attribute__((ext_vector_type(4))) float floatx4;
typedef unsigned long long ull;

__device__ __forceinline__ unsigned short f2bf(float f) {
    unsigned u = __float_as_uint(f);
    unsigned r = u + 0x7fffu + ((u >> 16) & 1u);   // RNE
    return (unsigned short)(r >> 16);
}
__device__ __forceinline__ float bf2f(unsigned short h) {
    return __uint_as_float(((unsigned)h) << 16);
}
__device__ __forceinline__ float fast_tanh(float x) {
    float e = __expf(2.0f * x);
    return 1.0f - 2.0f * __builtin_amdgcn_rcpf(e + 1.0f);
}
__device__ __forceinline__ bf16x8 as_bf(floatx4 v) {
    union { floatx4 f; bf16x8 b; } u; u.f = v; return u.b;
}

// ---- prep kernels -------------------------------------------------------
__global__ void k_wsplit(const float* __restrict__ whh, const float* __restrict__ mask,
                         unsigned short* __restrict__ hi, unsigned short* __restrict__ lo, int n) {
    int i = blockIdx.x * blockDim.x + threadIdx.x;
    int stride = gridDim.x * blockDim.x;
    for (; i < n; i += stride) {
        float w = whh[i] * mask[i];
        unsigned short h = f2bf(w);
        hi[i] = h;
        lo[i] = f2bf(w - bf2f(h));
    }
}
__global__ void k_split(const float* __restrict__ src,
                        unsigned short* __restrict__ hi, unsigned short* __restrict__ lo, int n) {
    int i = blockIdx.x * blockDim.x + threadIdx.x;
    int stride = gridDim.x * blockDim.x;
    for (; i < n; i += stride) {
        float w = src[i];
        unsigned short h = f2bf(w);
        hi[i] = h;
        lo[i] = f2bf(w - bf2f(h));
    }
}
__global__ void k_cast(const float* __restrict__ src, unsigned short* __restrict__ dst, int n) {
    int i = blockIdx.x * blockDim.x + threadIdx.x;
    int stride = gridDim.x * blockDim.x;
    for (; i < n; i += stride) dst[i] = f2bf(src[i]);
}

// ---- persistent recurrence kernel --------------------------------------
// 256 WGs x 512 thr (8 waves). 84 KB LDS forces 1 WG/CU => exactly 32 WGs
// per XCD. WGs self-organize into NREP=8 replicas by HW_REG_XCC_ID + slot
// claim; replica r owns batch rows [8r,8r+8) for ALL 512 steps (batch rows
// are independent recurrent chains => replicas never sync with each other).
// Within a replica: WG slot s owns cols [64s,64s+64); wave w owns k-slice
// [256w,256w+256) and waits on only 4 producer WGs' flags.
// Memory protocol = round-5 proven: sc1 write-through h stores + per-wave
// vmcnt drain + flag store (agent); consumer h loads are PLAIN (fresh
// addresses each t). Poll is dual-read (sc0 L2 fast path + sc0.sc1 MALL
// truth, take max) so correctness never depends on the XCD mapping.
// W hi/lo lives in REGISTERS (64 bf16x8 frags/wave, asm-pinned).
__global__ __launch_bounds__(NTHREADS, 2) void k_rnn(
    const unsigned short* __restrict__ whi, const unsigned short* __restrict__ wlo,
    const unsigned short* __restrict__ wihh, const unsigned short* __restrict__ wihl,
    const unsigned short* __restrict__ xbf, const float* __restrict__ bih,
    unsigned short* hs, unsigned int* flags, unsigned int* slotctr)
{
    extern __shared__ char smem[];
    float* sRed0 = (float*)smem;                 // 8 waves * RWAVE
    float* sRed1 = sRed0 + 8 * RWAVE;
    float* sBih  = sRed1 + 8 * RWAVE;            // 64
    int*   sMeta = (int*)(sBih + 64);            // rep, slot

    const int tid  = threadIdx.x;
    const int w    = tid >> 6;
    const int lane = tid & 63;
    const int q    = lane >> 4;
    const int nn   = lane & 15;
    const int row8 = lane & 7;        // A-operand batch row (rows 8-15 dup)

    if (tid == 0) {
        unsigned xcc = __builtin_amdgcn_s_getreg((31u << 11) | 20u) & 7u; // HW_REG_XCC_ID
        sMeta[0] = (int)xcc;
        sMeta[1] = (int)atomicAdd(&slotctr[xcc], 1u);
    }
    __syncthreads();
    const int rep  = sMeta[0];
    const int slot = sMeta[1];
    if (slot >= WPR) return;          // can't happen with 1 WG/CU, but safe
    const int j0   = slot * COLS;
    const int kb   = w * 256;         // this wave's k range in H

    if (tid < COLS) sBih[tid] = bih[j0 + tid];

    unsigned short* hsrep = hs + (size_t)rep * (S_ + 1) * SLABX;
    unsigned int*   frep  = flags + rep * FST;

    // ---- W hi/lo fragments into registers, pinned ----
    floatx4 wfh[4][8], wfl[4][8];     // [ntile][k-chunk]
#pragma unroll
    for (int nt = 0; nt < 4; ++nt) {
        const size_t row = (size_t)(j0 + nt * 16 + nn) * H_ + (size_t)(kb + q * 8);
#pragma unroll
        for (int c = 0; c < 8; ++c) {
            wfh[nt][c] = *(const floatx4*)&whi[row + c * 32];
            wfl[nt][c] = *(const floatx4*)&wlo[row + c * 32];
            asm volatile("" : "+v"(wfh[nt][c]), "+v"(wfl[nt][c]));
        }
    }
    // x-projection W frags: waves 0..3 cover I in 32-chunks
    floatx4 bxh[4], bxl[4];
    if (w < 4) {
#pragma unroll
        for (int nt = 0; nt < 4; ++nt) {
            const size_t row = (size_t)(j0 + nt * 16 + nn) * I_ + (size_t)(w * 32 + q * 8);
            bxh[nt] = *(const floatx4*)&wihh[row];
            bxl[nt] = *(const floatx4*)&wihl[row];
            asm volatile("" : "+v"(bxh[nt]), "+v"(bxl[nt]));
        }
    }

#pragma unroll 1
    for (int t = 0; t < S_; ++t) {
        floatx4 a0 = {0.f, 0.f, 0.f, 0.f}, a1 = a0, a2 = a0, a3 = a0;

        // h-independent x-projection first (overlaps producer latency)
        if (w < 4) {
            bf16x8 xa = *(const bf16x8*)&xbf[(size_t)(rep * ROWS + row8) * (S_ * I_)
                                             + (size_t)t * I_ + w * 32 + q * 8];
            a0 = __builtin_amdgcn_mfma_f32_16x16x32_bf16(xa, as_bf(bxh[0]), a0, 0, 0, 0);
            a1 = __builtin_amdgcn_mfma_f32_16x16x32_bf16(xa, as_bf(bxh[1]), a1, 0, 0, 0);
            a2 = __builtin_amdgcn_mfma_f32_16x16x32_bf16(xa, as_bf(bxh[2]), a2, 0, 0, 0);
            a3 = __builtin_amdgcn_mfma_f32_16x16x32_bf16(xa, as_bf(bxh[3]), a3, 0, 0, 0);
            a0 = __builtin_amdgcn_mfma_f32_16x16x32_bf16(xa, as_bf(bxl[0]), a0, 0, 0, 0);
            a1 = __builtin_amdgcn_mfma_f32_16x16x32_bf16(xa, as_bf(bxl[1]), a1, 0, 0, 0);
            a2 = __builtin_amdgcn_mfma_f32_16x16x32_bf16(xa, as_bf(bxl[2]), a2, 0, 0, 0);
            a3 = __builtin_amdgcn_mfma_f32_16x16x32_bf16(xa, as_bf(bxl[3]), a3, 0, 0, 0);
        }

        // wait for this wave's 4 producer WGs (slots 4w..4w+4) to publish t
        if (t > 0) {
            const unsigned want = (unsigned)t;
            const unsigned int* fp = &frep[4 * w + (lane & 3)];
            int iters = 0;
            for (;;) {
                unsigned v = want;
                if (lane < 4) {
                    unsigned v0, v1;
                    asm volatile("global_load_dword %0, %2, off sc0\n\t"
                                 "global_load_dword %1, %2, off sc0 sc1\n\t"
                                 "s_waitcnt vmcnt(0)"
                                 : "=&v"(v0), "=&v"(v1) : "v"(fp) : "memory");
                    v = v0 > v1 ? v0 : v1;   // monotonic: max is freshest
                }
                if (__ballot(v < want) == 0ull) break;
                if (++iters > (1 << 14)) break;   // anti-hang valve
            }
        }

        // recurrent K-slice: 8 chunks, W from registers, h plain loads
        const unsigned short* hp = hsrep + (size_t)t * SLABX + (size_t)row8 * H_ + kb + q * 8;
#pragma unroll
        for (int c = 0; c < 8; ++c) {
            bf16x8 ha = *(const bf16x8*)&hp[c * 32];
            a0 = __builtin_amdgcn_mfma_f32_16x16x32_bf16(ha, as_bf(wfh[0][c]), a0, 0, 0, 0);
            a1 = __builtin_amdgcn_mfma_f32_16x16x32_bf16(ha, as_bf(wfh[1][c]), a1, 0, 0, 0);
            a2 = __builtin_amdgcn_mfma_f32_16x16x32_bf16(ha, as_bf(wfh[2][c]), a2, 0, 0, 0);
            a3 = __builtin_amdgcn_mfma_f32_16x16x32_bf16(ha, as_bf(wfh[3][c]), a3, 0, 0, 0);
            a0 = __builtin_amdgcn_mfma_f32_16x16x32_bf16(ha, as_bf(wfl[0][c]), a0, 0, 0, 0);
            a1 = __builtin_amdgcn_mfma_f32_16x16x32_bf16(ha, as_bf(wfl[1][c]), a1, 0, 0, 0);
            a2 = __builtin_amdgcn_mfma_f32_16x16x32_bf16(ha, as_bf(wfl[2][c]), a2, 0, 0, 0);
            a3 = __builtin_amdgcn_mfma_f32_16x16x32_bf16(ha, as_bf(wfl[3][c]), a3, 0, 0, 0);
        }

        // wave partials -> LDS. C rows m=q*4+r; only m<8 (q<2) are real.
        float* sr = (t & 1) ? sRed1 : sRed0;
        if (q < 2) {
#pragma unroll
            for (int r = 0; r < 4; ++r) {
                const int m = q * 4 + r;
                sr[w * RWAVE + m * RW +      nn] = a0[r];
                sr[w * RWAVE + m * RW + 16 + nn] = a1[r];
                sr[w * RWAVE + m * RW + 32 + nn] = a2[r];
                sr[w * RWAVE + m * RW + 48 + nn] = a3[r];
            }
        }
        __syncthreads();

        // reduce 8 waves, +bih, tanh, pack, sc1 8-B store (128 workers)
        if (tid < 128) {
            const int row = tid >> 4, c0 = (tid & 15) * 4;
            floatx4 s = {0.f, 0.f, 0.f, 0.f};
#pragma unroll
            for (int ww = 0; ww < 8; ++ww)
                s += *(const floatx4*)&sr[ww * RWAVE + row * RW + c0];
            union { unsigned short u4[4]; ull u64; } cv;
            cv.u4[0] = f2bf(fast_tanh(s[0] + sBih[c0 + 0]));
            cv.u4[1] = f2bf(fast_tanh(s[1] + sBih[c0 + 1]));
            cv.u4[2] = f2bf(fast_tanh(s[2] + sBih[c0 + 2]));
            cv.u4[3] = f2bf(fast_tanh(s[3] + sBih[c0 + 3]));
            ull* dst = (ull*)&hsrep[(size_t)(t + 1) * SLABX + (size_t)row * H_ + j0 + c0];
            __hip_atomic_store(dst, cv.u64, __ATOMIC_RELAXED, __HIP_MEMORY_SCOPE_AGENT);
        }
        asm volatile("s_waitcnt vmcnt(0)" ::: "memory");
        __syncthreads();
        if (tid == 0)
            __hip_atomic_store(&frep[slot], (unsigned)(t + 1),
                               __ATOMIC_RELAXED, __HIP_MEMORY_SCOPE_AGENT);
    }
}

// ---- output projection: out[b,t,o] = h(t+1)[b,:] . Who[o,:] + bho -------
__global__ __launch_bounds__(256) void k_out(
    const unsigned short* __restrict__ hsbase, const unsigned short* __restrict__ who,
    const float* __restrict__ bho, float* __restrict__ out)
{
    const int tid = threadIdx.x;
    const int w = tid >> 6, lane = tid & 63, q = lane >> 4, nn = lane & 15;
    const size_t r0 = ((size_t)blockIdx.x * 4 + w) * 16;   // rr = t*64+b
    const int t = (int)(r0 >> 6);
    const int b = (int)(r0 & 63) + nn;
    const unsigned short* arow = hsbase
        + ((size_t)(b >> 3) * (S_ + 1) + (size_t)(t + 1)) * SLABX + (size_t)(b & 7) * H_;
    floatx4 acc[8];
#pragma unroll
    for (int i = 0; i < 8; ++i) acc[i] = floatx4{0.f, 0.f, 0.f, 0.f};
    for (int ks = 0; ks < 64; ++ks) {
        const int kk = ks * 32 + q * 8;
        bf16x8 a = *(const bf16x8*)&arow[kk];
#pragma unroll
        for (int nt = 0; nt < 8; ++nt) {
            bf16x8 bb = *(const bf16x8*)&who[(size_t)(nt * 16 + nn) * H_ + kk];
            acc[nt] = __builtin_amdgcn_mfma_f32_16x16x32_bf16(a, bb, acc[nt], 0, 0, 0);
        }
    }
#pragma unroll
    for (int nt = 0; nt < 8; ++nt) {
#pragma unroll
        for (int r = 0; r < 4; ++r) {
            size_t rr = r0 + q * 4 + r;
            int tt = (int)(rr >> 6), bb = (int)(rr & 63);
            int o = nt * 16 + nn;
            out[(size_t)bb * (S_ * O_) + (size_t)tt * O_ + o] = acc[nt][r] + bho[o];
        }
    }
}

// ---- host ----------------------------------------------------------------
extern "C" void kernel_launch(void* const* d_in, const int* in_sizes, int n_in,
                              void* d_out, int out_size, void* d_ws, size_t ws_size,
                              hipStream_t stream) {
    const float* x    = (const float*)d_in[0];
    const float* Wih  = (const float*)d_in[1];
    const float* bih  = (const float*)d_in[2];
    const float* Whh  = (const float*)d_in[3];
    const float* Who  = (const float*)d_in[4];
    const float* bho  = (const float*)d_in[5];
    const float* mask = (const float*)d_in[6];
    float* out = (float*)d_out;

    char* ws = (char*)d_ws;
    constexpr size_t CTL_OFF  = 0;      // slotctr[8] @0, flags @1024
    constexpr size_t CTL_BYTES = 4096;
    constexpr size_t HS_OFF   = CTL_OFF + CTL_BYTES;
    constexpr size_t HS_BYTES = (size_t)NREP * (S_ + 1) * SLABX * 2;
    constexpr size_t WHI_OFF  = HS_OFF + HS_BYTES;
    constexpr size_t WLO_OFF  = WHI_OFF + (size_t)H_ * H_ * 2;
    constexpr size_t XBF_OFF  = WLO_OFF + (size_t)H_ * H_ * 2;
    constexpr size_t WIHH_OFF = XBF_OFF + (size_t)B_ * S_ * I_ * 2;
    constexpr size_t WIHL_OFF = WIHH_OFF + (size_t)H_ * I_ * 2;
    constexpr size_t WHO_OFF  = WIHL_OFF + (size_t)H_ * I_ * 2;
    constexpr size_t WS_NEED  = WHO_OFF + (size_t)O_ * H_ * 2;
    if (ws_size < WS_NEED) return;

    unsigned int*   slotctr = (unsigned int*)(ws + CTL_OFF);
    unsigned int*   flags   = (unsigned int*)(ws + CTL_OFF + 1024);
    unsigned short* hs      = (unsigned short*)(ws + HS_OFF);
    unsigned short* whi     = (unsigned short*)(ws + WHI_OFF);
    unsigned short* wlo     = (unsigned short*)(ws + WLO_OFF);
    unsigned short* xbf     = (unsigned short*)(ws + XBF_OFF);
    unsigned short* wihh    = (unsigned short*)(ws + WIHH_OFF);
    unsigned short* wihl    = (unsigned short*)(ws + WIHL_OFF);
    unsigned short* whobf   = (unsigned short*)(ws + WHO_OFF);

    hipMemsetAsync(ws + CTL_OFF, 0, CTL_BYTES, stream);   // slotctr + flags
    for (int r = 0; r < NREP; ++r)                        // h(0) = 0 per replica
        hipMemsetAsync(hs + (size_t)r * (S_ + 1) * SLABX, 0, (size_t)SLABX * 2, stream);

    k_wsplit<<<1024, 256, 0, stream>>>(Whh, mask, whi, wlo, H_ * H_);
    k_split <<<256, 256, 0, stream>>>(Wih, wihh, wihl, H_ * I_);
    k_cast  <<<256, 256, 0, stream>>>(Who, whobf, O_ * H_);
    k_cast  <<<1024, 256, 0, stream>>>(x, xbf, B_ * S_ * I_);

    constexpr int SMEM = 86016;   // 84 KB: forces 1 WG/CU -> 32 WGs/XCD
    hipFuncSetAttribute((const void*)k_rnn, hipFuncAttributeMaxDynamicSharedMemorySize, SMEM);
    k_rnn<<<NREP * WPR, NTHREADS, SMEM, stream>>>(whi, wlo, wihh, wihl, xbf, bih,
                                                  hs, flags, slotctr);
    k_out<<<512, 256, 0, stream>>>(hs, whobf, bho, out);
}